// Round 1
// baseline (1056.288 us; speedup 1.0000x reference)
//
#include <hip/hip_runtime.h>
#include <math.h>

// ---------------------------------------------------------------------------
// GraphSAGE 3-layer forward: mean-agg -> (mean@Wl + bl + h@Wr) -> L2norm -> ReLU
// N=100000 nodes, E=1600000 edges, dims 128->128->128->64, all fp32.
//
// Strategy:
//   1. Build CSR by destination (counting sort) once per launch:
//      histogram(deg) -> blocked exclusive scan -> fill sorted src list.
//   2. Per layer: gather-aggregate (wave per node, float2 per lane, no float
//      atomics), then fused linear+bias+L2norm+ReLU (weights from L1/L2,
//      node rows staged in LDS, 8 nodes per thread for weight-load reuse).
// ---------------------------------------------------------------------------

#define SCAN_BLK 1024

__global__ __launch_bounds__(256) void count_deg(const int* __restrict__ dst, int E,
                                                 int* __restrict__ deg) {
    int e = blockIdx.x * blockDim.x + threadIdx.x;
    if (e < E) atomicAdd(&deg[dst[e]], 1);
}

// inclusive scan within blocks of SCAN_BLK, emit block totals
__global__ __launch_bounds__(SCAN_BLK) void scan_block(const int* __restrict__ deg, int N,
                                                       int* __restrict__ incl,
                                                       int* __restrict__ bsum) {
    __shared__ int s[SCAN_BLK];
    int i = blockIdx.x * SCAN_BLK + threadIdx.x;
    int v = (i < N) ? deg[i] : 0;
    s[threadIdx.x] = v;
    __syncthreads();
    for (int off = 1; off < SCAN_BLK; off <<= 1) {
        int t = (threadIdx.x >= off) ? s[threadIdx.x - off] : 0;
        __syncthreads();
        s[threadIdx.x] += t;
        __syncthreads();
    }
    if (i < N) incl[i] = s[threadIdx.x];
    if (threadIdx.x == SCAN_BLK - 1) bsum[blockIdx.x] = s[SCAN_BLK - 1];
}

// exclusive scan of block sums (NB <= 256), single block of 256 threads
__global__ __launch_bounds__(256) void scan_bsum(int* __restrict__ bsum, int NB) {
    __shared__ int s[256];
    int v = (threadIdx.x < NB) ? bsum[threadIdx.x] : 0;
    s[threadIdx.x] = v;
    __syncthreads();
    for (int off = 1; off < 256; off <<= 1) {
        int t = (threadIdx.x >= off) ? s[threadIdx.x - off] : 0;
        __syncthreads();
        s[threadIdx.x] += t;
        __syncthreads();
    }
    if (threadIdx.x < NB) bsum[threadIdx.x] = s[threadIdx.x] - v;  // exclusive
}

__global__ __launch_bounds__(256) void finalize_scan(const int* __restrict__ incl,
                                                     const int* __restrict__ deg,
                                                     const int* __restrict__ bsum, int N,
                                                     int* __restrict__ row_start,
                                                     int* __restrict__ cursor) {
    int i = blockIdx.x * blockDim.x + threadIdx.x;
    if (i < N) {
        int rs = incl[i] - deg[i] + bsum[i / SCAN_BLK];
        row_start[i] = rs;
        cursor[i] = rs;
    }
}

__global__ __launch_bounds__(256) void fill_csr(const int* __restrict__ src,
                                                const int* __restrict__ dst, int E,
                                                int* __restrict__ cursor,
                                                int* __restrict__ srcs) {
    int e = blockIdx.x * blockDim.x + threadIdx.x;
    if (e < E) {
        int p = atomicAdd(&cursor[dst[e]], 1);
        srcs[p] = src[e];
    }
}

// One wave per node. Lane owns 2 feature channels (float2 => 512B/row coalesced).
__global__ __launch_bounds__(256) void aggregate(const float* __restrict__ h,
                                                 const int* __restrict__ row_start,
                                                 const int* __restrict__ deg,
                                                 const int* __restrict__ srcs,
                                                 float* __restrict__ mean, int N) {
    int wave = (blockIdx.x * blockDim.x + threadIdx.x) >> 6;
    int lane = threadIdx.x & 63;
    if (wave >= N) return;
    int start = row_start[wave];
    int cnt = deg[wave];
    const float2* hp = (const float2*)h;
    float2 acc0 = {0.f, 0.f}, acc1 = {0.f, 0.f};
    int e = 0;
    for (; e + 1 < cnt; e += 2) {
        int s0 = srcs[start + e];
        int s1 = srcs[start + e + 1];
        float2 v0 = hp[s0 * 64 + lane];
        float2 v1 = hp[s1 * 64 + lane];
        acc0.x += v0.x; acc0.y += v0.y;
        acc1.x += v1.x; acc1.y += v1.y;
    }
    if (e < cnt) {
        int s0 = srcs[start + e];
        float2 v0 = hp[s0 * 64 + lane];
        acc0.x += v0.x; acc0.y += v0.y;
    }
    float inv = 1.0f / fmaxf((float)cnt, 1.0f);
    float2 r;
    r.x = (acc0.x + acc1.x) * inv;
    r.y = (acc0.y + acc1.y) * inv;
    ((float2*)mean)[wave * 64 + lane] = r;
}

// Fused: out = L2norm(mean@Wl + bl + h@Wr) with optional ReLU.
// DIN fixed 128. Thread = output column; NT=8 nodes/thread (weight reuse).
template <int DOUT, int RELU>
__global__ __launch_bounds__(256) void sage_linear(const float* __restrict__ mean,
                                                   const float* __restrict__ h,
                                                   const float* __restrict__ Wl,
                                                   const float* __restrict__ bl,
                                                   const float* __restrict__ Wr,
                                                   float* __restrict__ out, int N) {
    constexpr int G = 256 / DOUT;   // column-groups per block
    constexpr int NT = 8;           // nodes per group
    constexpr int NPB = G * NT;     // nodes per block
    __shared__ float sM[NPB][128];
    __shared__ float sH[NPB][128];
    __shared__ float sSq[NPB];

    const int tid = threadIdx.x;
    const int col = tid % DOUT;
    const int g = tid / DOUT;
    const int node0 = blockIdx.x * NPB;

    if (tid < NPB) sSq[tid] = 0.0f;

    // cooperative load of node rows (zero-pad OOB nodes)
    constexpr int TOT4 = NPB * 32;  // float4 elements per matrix
    for (int i = tid; i < TOT4; i += 256) {
        int n = i >> 5;
        int c4 = i & 31;
        int gn = node0 + n;
        float4 mv = {0.f, 0.f, 0.f, 0.f}, hv = {0.f, 0.f, 0.f, 0.f};
        if (gn < N) {
            mv = ((const float4*)mean)[gn * 32 + c4];
            hv = ((const float4*)h)[gn * 32 + c4];
        }
        ((float4*)&sM[n][0])[c4] = mv;
        ((float4*)&sH[n][0])[c4] = hv;
    }
    __syncthreads();

    float acc[NT];
#pragma unroll
    for (int t = 0; t < NT; t++) acc[t] = 0.0f;

    const float* wlc = Wl + col;
    const float* wrc = Wr + col;
    for (int k = 0; k < 128; k += 4) {
        float wl0 = wlc[(k + 0) * DOUT];
        float wl1 = wlc[(k + 1) * DOUT];
        float wl2 = wlc[(k + 2) * DOUT];
        float wl3 = wlc[(k + 3) * DOUT];
        float wr0 = wrc[(k + 0) * DOUT];
        float wr1 = wrc[(k + 1) * DOUT];
        float wr2 = wrc[(k + 2) * DOUT];
        float wr3 = wrc[(k + 3) * DOUT];
#pragma unroll
        for (int t = 0; t < NT; t++) {
            int n = g * NT + t;
            float4 m = *(const float4*)&sM[n][k];
            float4 hh = *(const float4*)&sH[n][k];
            acc[t] += m.x * wl0 + m.y * wl1 + m.z * wl2 + m.w * wl3 +
                      hh.x * wr0 + hh.y * wr1 + hh.z * wr2 + hh.w * wr3;
        }
    }

    float bias = bl[col];
#pragma unroll
    for (int t = 0; t < NT; t++) {
        acc[t] += bias;
        float ss = acc[t] * acc[t];
#pragma unroll
        for (int off = 32; off > 0; off >>= 1) ss += __shfl_down(ss, off, 64);
        if ((tid & 63) == 0) atomicAdd(&sSq[g * NT + t], ss);
    }
    __syncthreads();

#pragma unroll
    for (int t = 0; t < NT; t++) {
        int n = g * NT + t;
        int gn = node0 + n;
        if (gn < N) {
            float nrm = sqrtf(sSq[n]);
            float v = acc[t] / fmaxf(nrm, 1e-12f);
            if (RELU) v = fmaxf(v, 0.0f);
            out[gn * DOUT + col] = v;
        }
    }
}

static inline size_t align_up(size_t x, size_t a) { return (x + a - 1) & ~(a - 1); }

extern "C" void kernel_launch(void* const* d_in, const int* in_sizes, int n_in,
                              void* d_out, int out_size, void* d_ws, size_t ws_size,
                              hipStream_t stream) {
    const int N = in_sizes[0] / 128;
    const int E = in_sizes[1] / 2;

    const float* x = (const float*)d_in[0];
    const int* ei = (const int*)d_in[1];
    const int* src = ei;
    const int* dst = ei + E;
    const float* Wl0 = (const float*)d_in[2];
    const float* bl0 = (const float*)d_in[3];
    const float* Wr0 = (const float*)d_in[4];
    const float* Wl1 = (const float*)d_in[5];
    const float* bl1 = (const float*)d_in[6];
    const float* Wr1 = (const float*)d_in[7];
    const float* Wl2 = (const float*)d_in[8];
    const float* bl2 = (const float*)d_in[9];
    const float* Wr2 = (const float*)d_in[10];
    float* out = (float*)d_out;

    // workspace carve-up
    char* w = (char*)d_ws;
    int* deg = (int*)w;       w += align_up((size_t)N * 4, 256);
    int* incl = (int*)w;      w += align_up((size_t)N * 4, 256);
    int* bsum = (int*)w;      w += align_up(256 * 4, 256);
    int* row_start = (int*)w; w += align_up((size_t)N * 4, 256);
    int* cursor = (int*)w;    w += align_up((size_t)N * 4, 256);
    int* srcs = (int*)w;      w += align_up((size_t)E * 4, 256);
    float* meanb = (float*)w; w += align_up((size_t)N * 128 * 4, 256);
    float* hA = (float*)w;    w += align_up((size_t)N * 128 * 4, 256);
    float* hB = (float*)w;    w += align_up((size_t)N * 128 * 4, 256);

    const int NB = (N + SCAN_BLK - 1) / SCAN_BLK;  // 98 for N=100000 (<=256)

    // ---- CSR build ----
    hipMemsetAsync(deg, 0, (size_t)N * 4, stream);
    count_deg<<<(E + 255) / 256, 256, 0, stream>>>(dst, E, deg);
    scan_block<<<NB, SCAN_BLK, 0, stream>>>(deg, N, incl, bsum);
    scan_bsum<<<1, 256, 0, stream>>>(bsum, NB);
    finalize_scan<<<(N + 255) / 256, 256, 0, stream>>>(incl, deg, bsum, N, row_start, cursor);
    fill_csr<<<(E + 255) / 256, 256, 0, stream>>>(src, dst, E, cursor, srcs);

    const int aggGrid = (N + 3) / 4;  // 4 waves/block, 1 node per wave

    // ---- layer 0: x -> hA (relu) ----
    aggregate<<<aggGrid, 256, 0, stream>>>(x, row_start, deg, srcs, meanb, N);
    sage_linear<128, 1><<<(N + 15) / 16, 256, 0, stream>>>(meanb, x, Wl0, bl0, Wr0, hA, N);

    // ---- layer 1: hA -> hB (relu) ----
    aggregate<<<aggGrid, 256, 0, stream>>>(hA, row_start, deg, srcs, meanb, N);
    sage_linear<128, 1><<<(N + 15) / 16, 256, 0, stream>>>(meanb, hA, Wl1, bl1, Wr1, hB, N);

    // ---- layer 2: hB -> out (no relu, dout=64) ----
    aggregate<<<aggGrid, 256, 0, stream>>>(hB, row_start, deg, srcs, meanb, N);
    sage_linear<64, 0><<<(N + 31) / 32, 256, 0, stream>>>(meanb, hB, Wl2, bl2, Wr2, out, N);
}

// Round 2
// 662.152 us; speedup vs baseline: 1.5952x; 1.5952x over previous
//
#include <hip/hip_runtime.h>
#include <math.h>

// ---------------------------------------------------------------------------
// GraphSAGE 3-layer forward, bf16-MFMA edition.
//   - activations stored bf16 (halves gather BW), fp32 accumulation everywhere
//   - linear = single [N x 256] @ [256 x DOUT] GEMM on mfma_f32_16x16x32_bf16
//     (A = [mean | h] concat-K, B = [Wl ; Wr] packed to frag order in LDS)
//   - fused bias + L2-norm (quad shuffle reduce) + ReLU epilogue
// ---------------------------------------------------------------------------

#define SCAN_BLK 1024

typedef __attribute__((ext_vector_type(8))) short short8;
typedef __attribute__((ext_vector_type(4))) float f32x4;

__device__ __forceinline__ unsigned f2bf_rtn(float f) {
    unsigned u = __float_as_uint(f);
    return (u + 0x7fffu + ((u >> 16) & 1u)) >> 16;  // round-to-nearest-even
}

// ---------------- CSR build (counting sort by dst) ----------------

__global__ __launch_bounds__(256) void count_deg(const int* __restrict__ dst, int E,
                                                 int* __restrict__ deg) {
    int e = blockIdx.x * blockDim.x + threadIdx.x;
    if (e < E) atomicAdd(&deg[dst[e]], 1);
}

__global__ __launch_bounds__(SCAN_BLK) void scan_block(const int* __restrict__ deg, int N,
                                                       int* __restrict__ incl,
                                                       int* __restrict__ bsum) {
    __shared__ int s[SCAN_BLK];
    int i = blockIdx.x * SCAN_BLK + threadIdx.x;
    int v = (i < N) ? deg[i] : 0;
    s[threadIdx.x] = v;
    __syncthreads();
    for (int off = 1; off < SCAN_BLK; off <<= 1) {
        int t = (threadIdx.x >= off) ? s[threadIdx.x - off] : 0;
        __syncthreads();
        s[threadIdx.x] += t;
        __syncthreads();
    }
    if (i < N) incl[i] = s[threadIdx.x];
    if (threadIdx.x == SCAN_BLK - 1) bsum[blockIdx.x] = s[SCAN_BLK - 1];
}

__global__ __launch_bounds__(256) void scan_bsum(int* __restrict__ bsum, int NB) {
    __shared__ int s[256];
    int v = (threadIdx.x < NB) ? bsum[threadIdx.x] : 0;
    s[threadIdx.x] = v;
    __syncthreads();
    for (int off = 1; off < 256; off <<= 1) {
        int t = (threadIdx.x >= off) ? s[threadIdx.x - off] : 0;
        __syncthreads();
        s[threadIdx.x] += t;
        __syncthreads();
    }
    if (threadIdx.x < NB) bsum[threadIdx.x] = s[threadIdx.x] - v;  // exclusive
}

__global__ __launch_bounds__(256) void finalize_scan(const int* __restrict__ incl,
                                                     const int* __restrict__ deg,
                                                     const int* __restrict__ bsum, int N,
                                                     int* __restrict__ row_start,
                                                     int* __restrict__ cursor) {
    int i = blockIdx.x * blockDim.x + threadIdx.x;
    if (i < N) {
        int rs = incl[i] - deg[i] + bsum[i / SCAN_BLK];
        row_start[i] = rs;
        cursor[i] = rs;
    }
}

__global__ __launch_bounds__(256) void fill_csr(const int* __restrict__ src,
                                                const int* __restrict__ dst, int E,
                                                int* __restrict__ cursor,
                                                int* __restrict__ srcs) {
    int e = blockIdx.x * blockDim.x + threadIdx.x;
    if (e < E) {
        int p = atomicAdd(&cursor[dst[e]], 1);
        srcs[p] = src[e];
    }
}

// ---------------- fp32 -> bf16 convert (x once per launch) ----------------

__global__ __launch_bounds__(256) void to_bf16(const float* __restrict__ in,
                                               unsigned short* __restrict__ out, int n4) {
    int i = blockIdx.x * blockDim.x + threadIdx.x;
    if (i < n4) {
        float4 v = ((const float4*)in)[i];
        ushort4 o;
        o.x = (unsigned short)f2bf_rtn(v.x);
        o.y = (unsigned short)f2bf_rtn(v.y);
        o.z = (unsigned short)f2bf_rtn(v.z);
        o.w = (unsigned short)f2bf_rtn(v.w);
        ((ushort4*)out)[i] = o;
    }
}

// ---------------- weight pack: [Wl;Wr] -> MFMA B-frag order ----------------
// B_packed[ks][nt][lane] holds 8 bf16: B[k=ks*32+(lane>>4)*8+j][n=nt*16+(lane&15)]

template <int DOUT>
__global__ __launch_bounds__(256) void pack_w(const float* __restrict__ Wl,
                                              const float* __restrict__ Wr,
                                              unsigned short* __restrict__ Bp) {
    constexpr int NT = DOUT / 16;
    int idx = blockIdx.x * blockDim.x + threadIdx.x;
    if (idx >= 8 * NT * 64) return;
    int lane = idx & 63;
    int nt = (idx >> 6) % NT;
    int ks = (idx >> 6) / NT;
    int n = nt * 16 + (lane & 15);
    int k0 = ks * 32 + (lane >> 4) * 8;
    unsigned short v[8];
#pragma unroll
    for (int j = 0; j < 8; j++) {
        int k = k0 + j;
        float w = (k < 128) ? Wl[k * DOUT + n] : Wr[(k - 128) * DOUT + n];
        v[j] = (unsigned short)f2bf_rtn(w);
    }
#pragma unroll
    for (int j = 0; j < 8; j++) Bp[(size_t)idx * 8 + j] = v[j];
}

// ---------------- aggregate: mean of bf16 neighbor rows ----------------
// one wave per node; lane owns 2 channels (one dword of bf16x2)

__global__ __launch_bounds__(256) void aggregate(const unsigned short* __restrict__ h,
                                                 const int* __restrict__ row_start,
                                                 const int* __restrict__ deg,
                                                 const int* __restrict__ srcs,
                                                 unsigned short* __restrict__ mean, int N) {
    int wave = (blockIdx.x * blockDim.x + threadIdx.x) >> 6;
    int lane = threadIdx.x & 63;
    if (wave >= N) return;
    int start = row_start[wave];
    int cnt = deg[wave];
    const unsigned* hp = (const unsigned*)h;
    float a0 = 0.f, b0 = 0.f, a1 = 0.f, b1 = 0.f;
    int e = 0;
    for (; e + 1 < cnt; e += 2) {
        unsigned v0 = hp[(size_t)srcs[start + e] * 64 + lane];
        unsigned v1 = hp[(size_t)srcs[start + e + 1] * 64 + lane];
        a0 += __uint_as_float(v0 << 16);
        b0 += __uint_as_float(v0 & 0xffff0000u);
        a1 += __uint_as_float(v1 << 16);
        b1 += __uint_as_float(v1 & 0xffff0000u);
    }
    if (e < cnt) {
        unsigned v0 = hp[(size_t)srcs[start + e] * 64 + lane];
        a0 += __uint_as_float(v0 << 16);
        b0 += __uint_as_float(v0 & 0xffff0000u);
    }
    float inv = 1.0f / fmaxf((float)cnt, 1.0f);
    float x = (a0 + a1) * inv;
    float y = (b0 + b1) * inv;
    unsigned o = f2bf_rtn(x) | (f2bf_rtn(y) << 16);
    ((unsigned*)mean)[(size_t)wave * 64 + lane] = o;
}

// ---------------- MFMA GEMM + bias + L2norm + ReLU ----------------
// A = [mean | h] (K=256, bf16, row-major 128 each), B = packed frags in LDS.
// Block: 4 waves x MT(2) row-tiles x 16 rows = 128 rows/block.

template <int DOUT, int RELU, int BF16OUT>
__global__ __launch_bounds__(256) void sage_gemm(const unsigned short* __restrict__ meanb,
                                                 const unsigned short* __restrict__ hb,
                                                 const unsigned short* __restrict__ Bp,
                                                 const float* __restrict__ bias,
                                                 void* __restrict__ outp, int N) {
    constexpr int NT = DOUT / 16;
    constexpr int MT = 2;
    __shared__ short Bl[8 * NT * 64 * 8];  // DOUT=128 -> 64KB

    const int tid = threadIdx.x;
    // stage packed B into LDS (straight copy, already frag-ordered)
    {
        const uint4* s = (const uint4*)Bp;
        uint4* d = (uint4*)Bl;
        constexpr int CNT = 8 * NT * 64;  // uint4 per frag
        for (int i = tid; i < CNT; i += 256) d[i] = s[i];
    }
    __syncthreads();

    const int wave = tid >> 6;
    const int lane = tid & 63;
    const int m = lane & 15;
    const int q = lane >> 4;
    const int rowbase = blockIdx.x * (64 * MT);

    int rowA[MT];
#pragma unroll
    for (int t = 0; t < MT; t++) rowA[t] = rowbase + (wave * MT + t) * 16 + m;

    f32x4 acc[MT][NT];
#pragma unroll
    for (int t = 0; t < MT; t++)
#pragma unroll
        for (int nt = 0; nt < NT; nt++) acc[t][nt] = (f32x4)0.0f;

#pragma unroll
    for (int ks = 0; ks < 8; ks++) {
        const unsigned short* ab = (ks < 4) ? meanb : hb;
        const int koff = (ks & 3) * 32 + q * 8;
        short8 afrag[MT];
#pragma unroll
        for (int t = 0; t < MT; t++) {
            if (rowA[t] < N)
                afrag[t] = *(const short8*)(ab + (size_t)rowA[t] * 128 + koff);
            else
                afrag[t] = (short8)(short)0;
        }
#pragma unroll
        for (int nt = 0; nt < NT; nt++) {
            short8 bfrag = *(const short8*)&Bl[((ks * NT + nt) * 64 + lane) * 8];
#pragma unroll
            for (int t = 0; t < MT; t++)
                acc[t][nt] = __builtin_amdgcn_mfma_f32_16x16x32_bf16(afrag[t], bfrag,
                                                                     acc[t][nt], 0, 0, 0);
        }
    }

    // epilogue: +bias, L2 norm over row (reduce over NT in-lane, then quad lanes)
    float bs[NT];
#pragma unroll
    for (int nt = 0; nt < NT; nt++) bs[nt] = bias[nt * 16 + m];

#pragma unroll
    for (int t = 0; t < MT; t++) {
        float ss[4] = {0.f, 0.f, 0.f, 0.f};
#pragma unroll
        for (int nt = 0; nt < NT; nt++)
#pragma unroll
            for (int r = 0; r < 4; r++) {
                acc[t][nt][r] += bs[nt];
                ss[r] += acc[t][nt][r] * acc[t][nt][r];
            }
#pragma unroll
        for (int msk = 1; msk < 16; msk <<= 1)
#pragma unroll
            for (int r = 0; r < 4; r++) ss[r] += __shfl_xor(ss[r], msk, 64);
        float rinv[4];
#pragma unroll
        for (int r = 0; r < 4; r++) rinv[r] = 1.0f / fmaxf(sqrtf(ss[r]), 1e-12f);

#pragma unroll
        for (int r = 0; r < 4; r++) {
            int row = rowbase + (wave * MT + t) * 16 + q * 4 + r;
            if (row < N) {
#pragma unroll
                for (int nt = 0; nt < NT; nt++) {
                    float v = acc[t][nt][r] * rinv[r];
                    if (RELU) v = fmaxf(v, 0.0f);
                    int col = nt * 16 + m;
                    if (BF16OUT)
                        ((unsigned short*)outp)[(size_t)row * DOUT + col] =
                            (unsigned short)f2bf_rtn(v);
                    else
                        ((float*)outp)[(size_t)row * DOUT + col] = v;
                }
            }
        }
    }
}

static inline size_t align_up(size_t x, size_t a) { return (x + a - 1) & ~(a - 1); }

extern "C" void kernel_launch(void* const* d_in, const int* in_sizes, int n_in,
                              void* d_out, int out_size, void* d_ws, size_t ws_size,
                              hipStream_t stream) {
    const int N = in_sizes[0] / 128;
    const int E = in_sizes[1] / 2;

    const float* x = (const float*)d_in[0];
    const int* ei = (const int*)d_in[1];
    const int* src = ei;
    const int* dst = ei + E;
    const float* Wl0 = (const float*)d_in[2];
    const float* bl0 = (const float*)d_in[3];
    const float* Wr0 = (const float*)d_in[4];
    const float* Wl1 = (const float*)d_in[5];
    const float* bl1 = (const float*)d_in[6];
    const float* Wr1 = (const float*)d_in[7];
    const float* Wl2 = (const float*)d_in[8];
    const float* bl2 = (const float*)d_in[9];
    const float* Wr2 = (const float*)d_in[10];
    float* out = (float*)d_out;

    // workspace carve-up
    char* w = (char*)d_ws;
    int* deg = (int*)w;                 w += align_up((size_t)N * 4, 256);
    int* incl = (int*)w;                w += align_up((size_t)N * 4, 256);
    int* bsum = (int*)w;                w += align_up(256 * 4, 256);
    int* row_start = (int*)w;           w += align_up((size_t)N * 4, 256);
    int* cursor = (int*)w;              w += align_up((size_t)N * 4, 256);
    int* srcs = (int*)w;                w += align_up((size_t)E * 4, 256);
    unsigned short* xbf = (unsigned short*)w;   w += align_up((size_t)N * 128 * 2, 256);
    unsigned short* hA = (unsigned short*)w;    w += align_up((size_t)N * 128 * 2, 256);
    unsigned short* hB = (unsigned short*)w;    w += align_up((size_t)N * 128 * 2, 256);
    unsigned short* meanb = (unsigned short*)w; w += align_up((size_t)N * 128 * 2, 256);
    unsigned short* Bp0 = (unsigned short*)w;   w += align_up(8 * 8 * 64 * 8 * 2, 256);
    unsigned short* Bp1 = (unsigned short*)w;   w += align_up(8 * 8 * 64 * 8 * 2, 256);
    unsigned short* Bp2 = (unsigned short*)w;   w += align_up(8 * 4 * 64 * 8 * 2, 256);

    const int NB = (N + SCAN_BLK - 1) / SCAN_BLK;

    // ---- CSR build + conversions/packs ----
    hipMemsetAsync(deg, 0, (size_t)N * 4, stream);
    count_deg<<<(E + 255) / 256, 256, 0, stream>>>(dst, E, deg);
    to_bf16<<<(N * 32 + 255) / 256, 256, 0, stream>>>(x, xbf, N * 32);
    pack_w<128><<<(8 * 8 * 64 + 255) / 256, 256, 0, stream>>>(Wl0, Wr0, Bp0);
    pack_w<128><<<(8 * 8 * 64 + 255) / 256, 256, 0, stream>>>(Wl1, Wr1, Bp1);
    pack_w<64><<<(8 * 4 * 64 + 255) / 256, 256, 0, stream>>>(Wl2, Wr2, Bp2);
    scan_block<<<NB, SCAN_BLK, 0, stream>>>(deg, N, incl, bsum);
    scan_bsum<<<1, 256, 0, stream>>>(bsum, NB);
    finalize_scan<<<(N + 255) / 256, 256, 0, stream>>>(incl, deg, bsum, N, row_start, cursor);
    fill_csr<<<(E + 255) / 256, 256, 0, stream>>>(src, dst, E, cursor, srcs);

    const int aggGrid = (N + 3) / 4;         // 4 waves/block, 1 node/wave
    const int gemmGrid = (N + 127) / 128;    // 128 rows/block

    // ---- layer 0: x -> hA (relu, bf16 out) ----
    aggregate<<<aggGrid, 256, 0, stream>>>(xbf, row_start, deg, srcs, meanb, N);
    sage_gemm<128, 1, 1><<<gemmGrid, 256, 0, stream>>>(meanb, xbf, Bp0, bl0, hA, N);

    // ---- layer 1: hA -> hB (relu, bf16 out) ----
    aggregate<<<aggGrid, 256, 0, stream>>>(hA, row_start, deg, srcs, meanb, N);
    sage_gemm<128, 1, 1><<<gemmGrid, 256, 0, stream>>>(meanb, hA, Bp1, bl1, hB, N);

    // ---- layer 2: hB -> out (no relu, fp32 out) ----
    aggregate<<<aggGrid, 256, 0, stream>>>(hB, row_start, deg, srcs, meanb, N);
    sage_gemm<64, 0, 0><<<gemmGrid, 256, 0, stream>>>(meanb, hB, Bp2, bl2, out, N);
}